// Round 12
// baseline (39.580 us; speedup 1.0000x reference)
//
#include <hip/hip_runtime.h>
#include <hip/hip_fp16.h>

#define INPUT_SIZE 128
#define NUM_REL 16

typedef int      i32x4  __attribute__((ext_vector_type(4)));
typedef float    f32x4  __attribute__((ext_vector_type(4)));
typedef _Float16 f16x8  __attribute__((ext_vector_type(8)));

// ---------------------------------------------------------------------------
// Kernel 0: pack w into fp16 MFMA B-fragments, lane-contiguous.
//   Bpk[((t*4+ks)*64 + lane)*8 + e] = (f16) w[(t*128 + ks*32 + (lane>>4)*8 + e)*16 + (lane&15)]
// 4096 halves = 8 KB. One 256-thread block, 16 elements/thread.
// ---------------------------------------------------------------------------
__global__ __launch_bounds__(256) void pack_b_kernel(
    const float* __restrict__ w,     // (256,16) row-major
    __half* __restrict__ Bpk)        // 4096 halves
{
    const int tid = threadIdx.x;
    #pragma unroll
    for (int i = 0; i < 16; ++i) {
        const int idx  = tid * 16 + i;          // 0..4095
        const int e    = idx & 7;
        const int lane = (idx >> 3) & 63;
        const int ks   = (idx >> 9) & 3;
        const int t    = idx >> 11;
        const int ln   = lane & 15;
        const int kg   = lane >> 4;
        const int k    = ks * 32 + kg * 8 + e;
        Bpk[idx] = __float2half(w[(size_t)(t * INPUT_SIZE + k) * NUM_REL + ln]);
    }
}

// ---------------------------------------------------------------------------
// Kernel 1 v3 (MFMA): L[n][0:16) = x[n].w_src, L[n][16:32) = x[n].w_dst.
// Per wave: one 16-node tile. B-frags = 8 coalesced 16B loads from Bpk
// (L2-hot). A-frags = 8 x 16B loads from x + packed converts. 8 MFMA.
// No LDS, no barriers, no redundant w work (R11's 64 scalar w-loads/thread
// was the k1 cost driver hypothesis).
// ---------------------------------------------------------------------------
__global__ __launch_bounds__(256) void node_logits_mfma(
    const float* __restrict__ x,
    const __half* __restrict__ Bpk,  // packed B fragments (8 KB)
    __half* __restrict__ L,          // (num_nodes, 32) fp16
    int num_nodes)
{
    const int wave = threadIdx.x >> 6;
    const int lane = threadIdx.x & 63;
    const int m0 = (blockIdx.x * 4 + wave) * 16;
    if (m0 >= num_nodes) return;

    const int ln = lane & 15;        // A-row / B-col / D-col
    const int kg = lane >> 4;        // k-group 0..3

    // B fragments: one 16B vector load each, lane-contiguous.
    const f16x8* bv = (const f16x8*)Bpk;
    f16x8 bfrag[2][4];
    #pragma unroll
    for (int t = 0; t < 2; ++t)
        #pragma unroll
        for (int ks = 0; ks < 4; ++ks)
            bfrag[t][ks] = bv[(t * 4 + ks) * 64 + lane];

    // A fragments: row m0+ln (clamped; stores predicated).
    const int row = (m0 + ln < num_nodes) ? (m0 + ln) : (num_nodes - 1);
    const float* xr = x + (size_t)row * INPUT_SIZE;
    f16x8 afrag[4];
    #pragma unroll
    for (int ks = 0; ks < 4; ++ks) {
        const f32x4 lo = *(const f32x4*)(xr + ks * 32 + kg * 8);
        const f32x4 hi = *(const f32x4*)(xr + ks * 32 + kg * 8 + 4);
        #pragma unroll
        for (int e = 0; e < 4; ++e) {
            afrag[ks][e]     = (_Float16)lo[e];
            afrag[ks][4 + e] = (_Float16)hi[e];
        }
    }

    f32x4 acc0 = {0.f, 0.f, 0.f, 0.f};
    f32x4 acc1 = {0.f, 0.f, 0.f, 0.f};
    #pragma unroll
    for (int ks = 0; ks < 4; ++ks) {
        acc0 = __builtin_amdgcn_mfma_f32_16x16x32_f16(afrag[ks], bfrag[0][ks], acc0, 0, 0, 0);
        acc1 = __builtin_amdgcn_mfma_f32_16x16x32_f16(afrag[ks], bfrag[1][ks], acc1, 0, 0, 0);
    }

    // Store: node r = m0 + kg*4 + q; rel = ln (acc0) / 16+ln (acc1).
    #pragma unroll
    for (int q = 0; q < 4; ++q) {
        const int r = m0 + kg * 4 + q;
        if (r < num_nodes) {
            L[(size_t)r * 32 + ln]      = __float2half(acc0[q]);
            L[(size_t)r * 32 + 16 + ln] = __float2half(acc1[q]);
        }
    }
}

// ---------------------------------------------------------------------------
// Kernel 2: R2's edge kernel VERBATIM (measured ~13.5 us). 8 edges/thread,
// fp16 table gathers, plain loads/stores.
// ---------------------------------------------------------------------------
__global__ __launch_bounds__(256) void edge_score_kernel(
    const int* __restrict__ ei,      // (2, E) int32
    const int* __restrict__ et,      // (E,) int32
    const __half* __restrict__ L,    // (N, 32) fp16
    float* __restrict__ out,
    int num_edges)
{
    const int i = blockIdx.x * blockDim.x + threadIdx.x;   // octet index
    if (i * 8 >= num_edges) return;

    const i32x4* eis = (const i32x4*)ei;
    const i32x4* eid = (const i32x4*)(ei + num_edges);
    const i32x4* ett = (const i32x4*)et;

    const i32x4 sa = eis[2 * i], sb = eis[2 * i + 1];
    const i32x4 da = eid[2 * i], db = eid[2 * i + 1];
    const i32x4 ta = ett[2 * i], tb = ett[2 * i + 1];

    int s[8], d[8], t[8];
    #pragma unroll
    for (int j = 0; j < 4; ++j) {
        s[j] = sa[j]; s[4 + j] = sb[j];
        d[j] = da[j]; d[4 + j] = db[j];
        t[j] = ta[j]; t[4 + j] = tb[j];
    }

    __half hs[8], hd[8];
    #pragma unroll
    for (int j = 0; j < 8; ++j) hs[j] = L[(size_t)s[j] * 32 + t[j]];
    #pragma unroll
    for (int j = 0; j < 8; ++j) hd[j] = L[(size_t)d[j] * 32 + 16 + t[j]];

    f32x4 r[2];
    #pragma unroll
    for (int j = 0; j < 8; ++j) {
        const float sc = __half2float(hs[j]) + __half2float(hd[j]);
        const float att = 1.f / (1.f + __expf(-sc));
        r[j >> 2][j & 3] = fminf(fmaxf(att, 1e-5f), 0.99999f);
    }
    f32x4* o = (f32x4*)out;
    o[2 * i]     = r[0];
    o[2 * i + 1] = r[1];
}

// Fallback: direct per-edge dot product in f32 (no workspace).
__global__ void edge_direct_kernel(const float* __restrict__ x,
                                   const float* __restrict__ w,
                                   const int* __restrict__ ei,
                                   const int* __restrict__ et,
                                   float* __restrict__ out,
                                   int num_edges) {
    const int e = blockIdx.x * blockDim.x + threadIdx.x;
    if (e >= num_edges) return;
    const int s = ei[e];
    const int d = ei[num_edges + e];
    const int t = et[e];
    const float* xs = x + (size_t)s * INPUT_SIZE;
    const float* xd = x + (size_t)d * INPUT_SIZE;
    float acc = 0.f;
    #pragma unroll 4
    for (int k = 0; k < INPUT_SIZE; ++k)
        acc += xs[k] * w[k * NUM_REL + t] + xd[k] * w[(INPUT_SIZE + k) * NUM_REL + t];
    const float att = 1.f / (1.f + __expf(-acc));
    out[e] = fminf(fmaxf(att, 1e-5f), 0.99999f);
}

extern "C" void kernel_launch(void* const* d_in, const int* in_sizes, int n_in,
                              void* d_out, int out_size, void* d_ws, size_t ws_size,
                              hipStream_t stream) {
    const float* x  = (const float*)d_in[0];   // (50000, 128) f32
    const float* w  = (const float*)d_in[1];   // (256, 16) f32
    const int*   ei = (const int*)d_in[2];     // (2, E) int32
    const int*   et = (const int*)d_in[3];     // (E,) int32
    float* out = (float*)d_out;

    const int num_nodes = in_sizes[0] / INPUT_SIZE;
    const int num_edges = in_sizes[3];

    const size_t bpk_bytes = 4096 * sizeof(__half);                       // 8 KB
    const size_t tbl_bytes = (size_t)num_nodes * 32 * sizeof(__half);     // 3.2 MB
    const size_t ws_needed = bpk_bytes + tbl_bytes;

    if (ws_size >= ws_needed && (num_edges & 7) == 0) {
        __half* Bpk = (__half*)d_ws;
        __half* L   = (__half*)((char*)d_ws + bpk_bytes);

        pack_b_kernel<<<1, 256, 0, stream>>>(w, Bpk);

        const int blocks1 = (num_nodes + 63) / 64;   // 64 nodes per block
        node_logits_mfma<<<blocks1, 256, 0, stream>>>(x, Bpk, L, num_nodes);

        const int octs    = num_edges / 8;
        const int blocks2 = (octs + 255) / 256;
        edge_score_kernel<<<blocks2, 256, 0, stream>>>(ei, et, L, out, num_edges);
    } else {
        const int blocks = (num_edges + 255) / 256;
        edge_direct_kernel<<<blocks, 256, 0, stream>>>(x, w, ei, et, out, num_edges);
    }
}